// Round 12
// baseline (317.625 us; speedup 1.0000x reference)
//
#include <hip/hip_runtime.h>

#define T_SEQ 512
#define BATCH 4096
#define D_IN  5
#define H     15
#define G4    60   // 4*H
#define OUTN  25
#define XW_BYTES (T_SEQ * G4 * 4)   // 122880

#define M_SIG  (-1.4426950408889634f)   // sigmoid exp2 prescale
#define M_TANH (-2.8853901f)            // tanh exp2 prescale (-2*log2e)

// ---------- helpers ----------
__device__ __forceinline__ float fast_exp2(float x) {
#if __has_builtin(__builtin_amdgcn_exp2f)
  return __builtin_amdgcn_exp2f(x);
#else
  return exp2f(x);
#endif
}

__device__ __forceinline__ float fast_rcp(float x) {
#if __has_builtin(__builtin_amdgcn_rcpf)
  return __builtin_amdgcn_rcpf(x);
#else
  return 1.0f / x;
#endif
}

__device__ __forceinline__ float rl(float v, int lane) {
  return __int_as_float(__builtin_amdgcn_readlane(__float_as_int(v), lane));
}

// broadcast quad-lane K (0..3) to all 4 lanes of each quad via DPP quad_perm
template <int K>
__device__ __forceinline__ float qbcast(float v) {
  return __int_as_float(__builtin_amdgcn_update_dpp(
      0, __float_as_int(v), K * 0x55, 0xF, 0xF, true));
}

__device__ __forceinline__ unsigned long long shader_ticks() {
#if __has_builtin(__builtin_amdgcn_s_memtime)
  return __builtin_amdgcn_s_memtime();
#else
  return clock64();
#endif
}
__device__ __forceinline__ unsigned long long real_ticks() {
#if __has_builtin(__builtin_amdgcn_s_memrealtime)
  return __builtin_amdgcn_s_memrealtime();
#else
  return wall_clock64();
#endif
}

// ---------- clock probes (diagnostics; dur_us in rocprof IS the readout) ----
// probe_shader_clk: spins 120,000 SHADER cycles -> dur_us = 120000 / f_GHz / 1000
//   (50 us @ 2.4 GHz, 120 us @ 1.0 GHz, 240 us @ 0.5 GHz)
__global__ void __launch_bounds__(64, 1)
probe_shader_clk(unsigned long long* sink) {
  unsigned long long t0 = shader_ticks(), t;
  do { t = shader_ticks(); } while (t - t0 < 120000ULL);
  if (sink && threadIdx.x == 0) sink[0] = t - t0;
}
// probe_wall_clk: spins 2,500 REALTIME ticks -> 25.0 us if tick rate = 100 MHz
__global__ void __launch_bounds__(64, 1)
probe_wall_clk(unsigned long long* sink) {
  unsigned long long t0 = real_ticks(), t;
  do { t = real_ticks(); } while (t - t0 < 2500ULL);
  if (sink && threadIdx.x == 0) sink[1] = t - t0;
}

// ---------- kernel A ----------
// xw0[t][g] = (x[t,B-1,:]·w_ih0[g,:] + b_ih0[g] + b_hh0[g]) * m(g)
__global__ void precompute_xw0(const float* __restrict__ x,
                               const float* __restrict__ w_ih0,
                               const float* __restrict__ b_ih0,
                               const float* __restrict__ b_hh0,
                               float* __restrict__ xw0) {
  int idx = blockIdx.x * blockDim.x + threadIdx.x;
  if (idx >= T_SEQ * G4) return;
  int t = idx / G4;
  int g = idx - t * G4;
  const float* xp = x + ((size_t)t * BATCH + (BATCH - 1)) * D_IN;
  float a = b_ih0[g] + b_hh0[g];
#pragma unroll
  for (int d = 0; d < D_IN; ++d) a = fmaf(xp[d], w_ih0[g * D_IN + d], a);
  float m = (g / H == 2) ? M_TANH : M_SIG;
  xw0[idx] = a * m;
}

// ---------- kernel B: round-8 stage-skewed serial LSTM (proven, 146 us) ----
// lane = 4*unit + gate_type ; gate_type in {0:i, 1:f, 2:g(tanh), 3:o}
__global__ void __launch_bounds__(64, 1)
lstm_serial(const float* __restrict__ xw0,
            const float* __restrict__ w_hh0,
            const float* __restrict__ w_ih1,
            const float* __restrict__ w_hh1,
            const float* __restrict__ b_ih1,
            const float* __restrict__ b_hh1,
            const float* __restrict__ w_lin,
            const float* __restrict__ b_lin,
            float* __restrict__ out) {
  const int lane = threadIdx.x;
  const int ty = lane & 3;
  const int j  = lane >> 2;                  // unit 0..15 (15 = idle quad)
  const int g  = (j < H) ? (ty * H + j) : 0; // PyTorch gate row (i,f,g,o)

  const bool  isT  = (ty == 2);
  const float m    = isT ? M_TANH : M_SIG;
  const float scv  = isT ? (2.0f * M_TANH) : 1.0f;
  const float offv = isT ? (-M_TANH) : 0.0f;

  float w0[H], wi1[H], wh1[H];
#pragma unroll
  for (int k = 0; k < H; ++k) {
    w0[k]  = w_hh0[g * H + k] * m;
    wi1[k] = w_ih1[g * H + k] * m;
    wh1[k] = w_hh1[g * H + k] * m;
  }
  const float bias1 = (b_ih1[g] + b_hh1[g]) * m;

  float wl[H];
  {
    int o = (lane < OUTN) ? lane : 0;
#pragma unroll
    for (int k = 0; k < H; ++k) wl[k] = w_lin[o * H + k];
  }
  const float bl = b_lin[(lane < OUTN) ? lane : 0];

  float c0 = 0.0f, c1 = 0.0f;    // cell states, scaled by M_TANH
  float sh0[H], sh1[H];
#pragma unroll
  for (int k = 0; k < H; ++k) { sh0[k] = 0.0f; sh1[k] = 0.0f; }

  float h0v = 0.0f, h1v = 0.0f;

  auto L0 = [&](float xw) {
    float a0 = xw, a1 = 0.0f, a2 = 0.0f;
#pragma unroll
    for (int k = 0; k < 5; ++k)   a0 = fmaf(w0[k], sh0[k], a0);
#pragma unroll
    for (int k = 5; k < 10; ++k)  a1 = fmaf(w0[k], sh0[k], a1);
#pragma unroll
    for (int k = 10; k < 15; ++k) a2 = fmaf(w0[k], sh0[k], a2);
    float a = a0 + (a1 + a2);
    float e = fast_exp2(a);
    float s = fast_rcp(1.0f + e);
    float v = fmaf(s, scv, offv);
    float vi = qbcast<0>(v), vf = qbcast<1>(v), vg = qbcast<2>(v), vo = qbcast<3>(v);
    c0 = fmaf(vf, c0, vi * vg);
    float th = fmaf(fast_rcp(1.0f + fast_exp2(c0)), 2.0f, -1.0f);
    h0v = vo * th;
  };
  auto L1 = [&]() {
    float u0 = bias1, u1 = 0.0f, u2 = 0.0f, u3 = 0.0f, u4 = 0.0f, u5 = 0.0f;
#pragma unroll
    for (int k = 0; k < 5; ++k)   { u0 = fmaf(wi1[k], sh0[k], u0); u3 = fmaf(wh1[k], sh1[k], u3); }
#pragma unroll
    for (int k = 5; k < 10; ++k)  { u1 = fmaf(wi1[k], sh0[k], u1); u4 = fmaf(wh1[k], sh1[k], u4); }
#pragma unroll
    for (int k = 10; k < 15; ++k) { u2 = fmaf(wi1[k], sh0[k], u2); u5 = fmaf(wh1[k], sh1[k], u5); }
    float b = ((u0 + u1) + (u2 + u3)) + (u4 + u5);
    float e = fast_exp2(b);
    float s = fast_rcp(1.0f + e);
    float v = fmaf(s, scv, offv);
    float qi = qbcast<0>(v), qf = qbcast<1>(v), qg = qbcast<2>(v), qo = qbcast<3>(v);
    c1 = fmaf(qf, c1, qi * qg);
    float th = fmaf(fast_rcp(1.0f + fast_exp2(c1)), 2.0f, -1.0f);
    h1v = qo * th;
  };
  auto B0 = [&]() {
#pragma unroll
    for (int k = 0; k < H; ++k) sh0[k] = rl(h0v, 4 * k);
  };
  auto B1 = [&]() {
#pragma unroll
    for (int k = 0; k < H; ++k) sh1[k] = rl(h1v, 4 * k);
  };
  auto LIN = [&](int t2, bool do_store) {
    float o0 = bl, o1 = 0.0f, o2 = 0.0f;
#pragma unroll
    for (int k = 0; k < 5; ++k)   o0 = fmaf(wl[k], sh1[k], o0);
#pragma unroll
    for (int k = 5; k < 10; ++k)  o1 = fmaf(wl[k], sh1[k], o1);
#pragma unroll
    for (int k = 10; k < 15; ++k) o2 = fmaf(wl[k], sh1[k], o2);
    if (do_store && lane < OUTN) out[t2 * OUTN + lane] = o0 + (o1 + o2);
  };

  // prologue: i = 0 (L0 only)
  float xw_cur = xw0[g];
  float xw_n1  = xw0[1 * G4 + g];
  L0(xw_cur);
  B0();
  xw_cur = xw_n1;
  xw_n1  = xw0[2 * G4 + g];

  // main loop: i = 1 .. T-1
  for (int i = 1; i < T_SEQ; ++i) {
    int tn = (i + 2 < T_SEQ) ? (i + 2) : 0;
    float xw_n2 = xw0[tn * G4 + g];

    L1();                    // step i-1
    L0(xw_cur);              // step i
    LIN(i - 2, i >= 2);      // step i-2

    B0();
    B1();

    xw_cur = xw_n1;
    xw_n1  = xw_n2;
  }

  // epilogue
  LIN(T_SEQ - 2, true);
  L1();
  B1();
  LIN(T_SEQ - 1, true);
}

// ---------- launch ----------
extern "C" void kernel_launch(void* const* d_in, const int* in_sizes, int n_in,
                              void* d_out, int out_size, void* d_ws, size_t ws_size,
                              hipStream_t stream) {
  const float* x     = (const float*)d_in[0];
  const float* w_ih0 = (const float*)d_in[1];
  const float* w_hh0 = (const float*)d_in[2];
  const float* b_ih0 = (const float*)d_in[3];
  const float* b_hh0 = (const float*)d_in[4];
  const float* w_ih1 = (const float*)d_in[5];
  const float* w_hh1 = (const float*)d_in[6];
  const float* b_ih1 = (const float*)d_in[7];
  const float* b_hh1 = (const float*)d_in[8];
  const float* w_lin = (const float*)d_in[9];
  const float* b_lin = (const float*)d_in[10];
  float* out = (float*)d_out;
  float* xw0 = (float*)d_ws;  // 122880 B

  unsigned long long* sink = nullptr;
  if (ws_size >= (size_t)XW_BYTES + 2 * sizeof(unsigned long long))
    sink = (unsigned long long*)((char*)d_ws + XW_BYTES);

  precompute_xw0<<<dim3((T_SEQ * G4 + 255) / 256), dim3(256), 0, stream>>>(
      x, w_ih0, b_ih0, b_hh0, xw0);
  lstm_serial<<<dim3(1), dim3(64), 0, stream>>>(
      xw0, w_hh0, w_ih1, w_hh1, b_ih1, b_hh1, w_lin, b_lin, out);
  // clock probes: dur_us of these dispatches in rocprof = direct clock readout
  probe_shader_clk<<<dim3(1), dim3(64), 0, stream>>>(sink);
  probe_wall_clk<<<dim3(1), dim3(64), 0, stream>>>(sink);
}

// Round 13
// 248.216 us; speedup vs baseline: 1.2796x; 1.2796x over previous
//
#include <hip/hip_runtime.h>

#define T_SEQ 512
#define BATCH 4096
#define D_IN  5
#define H     15
#define G4    60   // 4*H
#define OUTN  25
#define XW_BYTES (T_SEQ * G4 * 4)     // 122880
#define H1_BYTES (T_SEQ * 16 * 4)     // 32768 (stride-16 padded h1 history)
#define TAG_BASE 0x5A000000

#define M_SIG  (-1.4426950408889634f)   // sigmoid exp2 prescale
#define M_TANH (-2.8853901f)            // tanh exp2 prescale (-2*log2e)

// ---------- helpers ----------
__device__ __forceinline__ float fast_exp2(float x) {
#if __has_builtin(__builtin_amdgcn_exp2f)
  return __builtin_amdgcn_exp2f(x);
#else
  return exp2f(x);
#endif
}
__device__ __forceinline__ float fast_rcp(float x) {
#if __has_builtin(__builtin_amdgcn_rcpf)
  return __builtin_amdgcn_rcpf(x);
#else
  return 1.0f / x;
#endif
}
__device__ __forceinline__ float rl(float v, int lane) {
  return __int_as_float(__builtin_amdgcn_readlane(__float_as_int(v), lane));
}
template <int K>
__device__ __forceinline__ float qbcast(float v) {
  return __int_as_float(__builtin_amdgcn_update_dpp(
      0, __float_as_int(v), K * 0x55, 0xF, 0xF, true));
}

// ---------- kernel A: xw0[t][g] = (x[t,B-1,:]·w_ih0[g,:] + biases) * m(g) ----
__global__ void precompute_xw0(const float* __restrict__ x,
                               const float* __restrict__ w_ih0,
                               const float* __restrict__ b_ih0,
                               const float* __restrict__ b_hh0,
                               float* __restrict__ xw0) {
  int idx = blockIdx.x * blockDim.x + threadIdx.x;
  if (idx >= T_SEQ * G4) return;
  int t = idx / G4;
  int g = idx - t * G4;
  const float* xp = x + ((size_t)t * BATCH + (BATCH - 1)) * D_IN;
  float a = b_ih0[g] + b_hh0[g];
#pragma unroll
  for (int d = 0; d < D_IN; ++d) a = fmaf(xp[d], w_ih0[g * D_IN + d], a);
  float m = (g / H == 2) ? M_TANH : M_SIG;
  xw0[idx] = a * m;
}

// ---------- kernel B: 2-wave flag-decoupled pipeline (no barriers in loop) --
// W0 (wave 0): layer-0, streams h0[t] + tag into LDS slot t (512 slots, no reuse).
// W1 (wave 1): layer-1, prefetches slot t+1 under compute of t; tag word is the
// last float of the slot's 4th 16B block, read FIRST so DS-FIFO order makes a
// matching tag prove the h-data reads (issued after) see completed writes.
// LIN offloaded to lin_out epilogue via h1 history in global scratch.
__global__ void __launch_bounds__(128, 1)
lstm_pipe2(const float* __restrict__ xw0,
           const float* __restrict__ w_hh0,
           const float* __restrict__ w_ih1,
           const float* __restrict__ w_hh1,
           const float* __restrict__ b_ih1,
           const float* __restrict__ b_hh1,
           const float* __restrict__ w_lin,
           const float* __restrict__ b_lin,
           float* __restrict__ out,
           float* __restrict__ h1g) {
  __shared__ __align__(16) float h0buf[T_SEQ][16];   // 32 KB; [15] = tag

  const int tid  = threadIdx.x;
  const int wid  = tid >> 6;
  const int lane = tid & 63;
  const int ty = lane & 3;
  const int j  = lane >> 2;                  // unit 0..15
  const int g  = (j < H) ? (ty * H + j) : 0; // PyTorch gate row (i,f,g,o)

  const bool  isT  = (ty == 2);
  const float m    = isT ? M_TANH : M_SIG;
  const float scv  = isT ? (2.0f * M_TANH) : 1.0f;
  const float offv = isT ? (-M_TANH) : 0.0f;

  // clear tags once, then the only barrier in the kernel
  for (int t = tid; t < T_SEQ; t += 128) h0buf[t][15] = 0.0f;
  __syncthreads();

  if (wid == 0) {
    // ---------------- W0: layer-0 producer ----------------
    float w0[H];
#pragma unroll
    for (int k = 0; k < H; ++k) w0[k] = w_hh0[g * H + k] * m;
    float sh0[H];
#pragma unroll
    for (int k = 0; k < H; ++k) sh0[k] = 0.0f;
    float c0 = 0.0f;
    float xw_cur = xw0[g];
    float xw_n1  = xw0[G4 + g];

    for (int t = 0; t < T_SEQ; ++t) {
      int tn = (t + 2 < T_SEQ) ? (t + 2) : 0;
      float xw_n2 = xw0[tn * G4 + g];

      float a0 = xw_cur, a1 = 0.0f, a2 = 0.0f;
#pragma unroll
      for (int k = 0; k < 5; ++k)   a0 = fmaf(w0[k], sh0[k], a0);
#pragma unroll
      for (int k = 5; k < 10; ++k)  a1 = fmaf(w0[k], sh0[k], a1);
#pragma unroll
      for (int k = 10; k < 15; ++k) a2 = fmaf(w0[k], sh0[k], a2);
      float a = a0 + (a1 + a2);
      float e = fast_exp2(a);
      float s = fast_rcp(1.0f + e);
      float v = fmaf(s, scv, offv);
      float vi = qbcast<0>(v), vf = qbcast<1>(v), vg = qbcast<2>(v), vo = qbcast<3>(v);
      c0 = fmaf(vf, c0, vi * vg);
      float th = fmaf(fast_rcp(1.0f + fast_exp2(c0)), 2.0f, -1.0f);
      float h0v = vo * th;   // identical across each quad (all inputs quad-uniform)

      // unpredicated data write: lanes j=15 scribble [15], tag write below wins
      h0buf[t][j] = h0v;
      asm volatile("" ::: "memory");               // keep program order
      h0buf[t][15] = __int_as_float(TAG_BASE + t); // all lanes, same value

#pragma unroll
      for (int k = 0; k < H; ++k) sh0[k] = rl(h0v, 4 * k);

      xw_cur = xw_n1;
      xw_n1  = xw_n2;
    }
  } else {
    // ---------------- W1: layer-1 consumer ----------------
    float wi1[H], wh1[H];
#pragma unroll
    for (int k = 0; k < H; ++k) {
      wi1[k] = w_ih1[g * H + k] * m;
      wh1[k] = w_hh1[g * H + k] * m;
    }
    const float bias1 = (b_ih1[g] + b_hh1[g]) * m;
    // fallback-LIN weights (used only if h1g == nullptr)
    float wl[H];
    {
      int o = (lane < OUTN) ? lane : 0;
#pragma unroll
      for (int k = 0; k < H; ++k) wl[k] = w_lin[o * H + k];
    }
    const float bl = b_lin[(lane < OUTN) ? lane : 0];

    float sh1[H];
#pragma unroll
    for (int k = 0; k < H; ++k) sh1[k] = 0.0f;
    float c1 = 0.0f;

    float4 n0 = {0,0,0,0}, n1 = {0,0,0,0}, n2 = {0,0,0,0}, n3 = {0,0,0,0};
    // n3.w bits = 0 -> guaranteed tag mismatch at t=0 -> poll path fetches slot 0

    for (int t = 0; t < T_SEQ; ++t) {
      float4 b0_ = n0, b1_ = n1, b2_ = n2, b3_ = n3;
      const int want = TAG_BASE + t;
      if (__float_as_int(b3_.w) != want) {
        // slow path (warmup only): poll tag, then re-read whole slot
        volatile const float* vt = &h0buf[t][15];
        int guard = 0;
        while (__float_as_int(*vt) != want && ++guard < (1 << 22)) {}
        asm volatile("" ::: "memory");
        const float4* p = (const float4*)&h0buf[t][0];
        b3_ = p[3];
        asm volatile("" ::: "memory");   // tag block read before data blocks
        b0_ = p[0]; b1_ = p[1]; b2_ = p[2];
      }
      // prefetch slot t+1 (tag block FIRST; latency hides under compute below)
      if (t + 1 < T_SEQ) {
        const float4* p = (const float4*)&h0buf[t + 1][0];
        n3 = p[3];
        asm volatile("" ::: "memory");
        n0 = p[0]; n1 = p[1]; n2 = p[2];
      }

      // layer-1 gates: wi1·h0[t] (VGPR blocks) + wh1·sh1 (+bias1)
      float u0 = bias1, u1 = 0.0f, u2 = 0.0f, u3 = 0.0f, u4 = 0.0f, u5 = 0.0f;
      u0 = fmaf(wi1[0],  b0_.x, u0); u0 = fmaf(wi1[1],  b0_.y, u0);
      u0 = fmaf(wi1[2],  b0_.z, u0); u0 = fmaf(wi1[3],  b0_.w, u0);
      u0 = fmaf(wi1[4],  b1_.x, u0);
      u1 = fmaf(wi1[5],  b1_.y, u1); u1 = fmaf(wi1[6],  b1_.z, u1);
      u1 = fmaf(wi1[7],  b1_.w, u1); u1 = fmaf(wi1[8],  b2_.x, u1);
      u1 = fmaf(wi1[9],  b2_.y, u1);
      u2 = fmaf(wi1[10], b2_.z, u2); u2 = fmaf(wi1[11], b2_.w, u2);
      u2 = fmaf(wi1[12], b3_.x, u2); u2 = fmaf(wi1[13], b3_.y, u2);
      u2 = fmaf(wi1[14], b3_.z, u2);
#pragma unroll
      for (int k = 0; k < 5; ++k)   u3 = fmaf(wh1[k], sh1[k], u3);
#pragma unroll
      for (int k = 5; k < 10; ++k)  u4 = fmaf(wh1[k], sh1[k], u4);
#pragma unroll
      for (int k = 10; k < 15; ++k) u5 = fmaf(wh1[k], sh1[k], u5);
      float b = ((u0 + u1) + (u2 + u3)) + (u4 + u5);

      float e = fast_exp2(b);
      float s = fast_rcp(1.0f + e);
      float v = fmaf(s, scv, offv);
      float qi = qbcast<0>(v), qf = qbcast<1>(v), qg = qbcast<2>(v), qo = qbcast<3>(v);
      c1 = fmaf(qf, c1, qi * qg);
      float th = fmaf(fast_rcp(1.0f + fast_exp2(c1)), 2.0f, -1.0f);
      float h1v = qo * th;

#pragma unroll
      for (int k = 0; k < H; ++k) sh1[k] = rl(h1v, 4 * k);

      if (h1g) {
        h1g[t * 16 + j] = h1v;   // unpredicated; j=15 lanes hit the pad slot
      } else {
        float o0 = bl, o1 = 0.0f, o2 = 0.0f;
#pragma unroll
        for (int k = 0; k < 5; ++k)   o0 = fmaf(wl[k], sh1[k], o0);
#pragma unroll
        for (int k = 5; k < 10; ++k)  o1 = fmaf(wl[k], sh1[k], o1);
#pragma unroll
        for (int k = 10; k < 15; ++k) o2 = fmaf(wl[k], sh1[k], o2);
        if (lane < OUTN) out[t * OUTN + lane] = o0 + (o1 + o2);
      }
    }
  }
}

// ---------- kernel C: LIN epilogue (parallel over t) ----------
__global__ void __launch_bounds__(64, 1)
lin_out(const float* __restrict__ h1g,
        const float* __restrict__ w_lin,
        const float* __restrict__ b_lin,
        float* __restrict__ out) {
  const int t = blockIdx.x;
  const int o = threadIdx.x;
  if (o >= OUTN) return;
  const float* hp = h1g + t * 16;
  float wl[H];
#pragma unroll
  for (int k = 0; k < H; ++k) wl[k] = w_lin[o * H + k];
  float o0 = b_lin[o], o1 = 0.0f, o2 = 0.0f;
#pragma unroll
  for (int k = 0; k < 5; ++k)   o0 = fmaf(wl[k], hp[k], o0);
#pragma unroll
  for (int k = 5; k < 10; ++k)  o1 = fmaf(wl[k], hp[k], o1);
#pragma unroll
  for (int k = 10; k < 15; ++k) o2 = fmaf(wl[k], hp[k], o2);
  out[t * OUTN + o] = o0 + (o1 + o2);
}

// ---------- launch ----------
extern "C" void kernel_launch(void* const* d_in, const int* in_sizes, int n_in,
                              void* d_out, int out_size, void* d_ws, size_t ws_size,
                              hipStream_t stream) {
  const float* x     = (const float*)d_in[0];
  const float* w_ih0 = (const float*)d_in[1];
  const float* w_hh0 = (const float*)d_in[2];
  const float* b_ih0 = (const float*)d_in[3];
  const float* b_hh0 = (const float*)d_in[4];
  const float* w_ih1 = (const float*)d_in[5];
  const float* w_hh1 = (const float*)d_in[6];
  const float* b_ih1 = (const float*)d_in[7];
  const float* b_hh1 = (const float*)d_in[8];
  const float* w_lin = (const float*)d_in[9];
  const float* b_lin = (const float*)d_in[10];
  float* out = (float*)d_out;
  float* xw0 = (float*)d_ws;  // 122880 B

  float* h1g = nullptr;
  if (ws_size >= (size_t)XW_BYTES + (size_t)H1_BYTES)
    h1g = (float*)((char*)d_ws + XW_BYTES);

  precompute_xw0<<<dim3((T_SEQ * G4 + 255) / 256), dim3(256), 0, stream>>>(
      x, w_ih0, b_ih0, b_hh0, xw0);
  lstm_pipe2<<<dim3(1), dim3(128), 0, stream>>>(
      xw0, w_hh0, w_ih1, w_hh1, b_ih1, b_hh1, w_lin, b_lin, out, h1g);
  if (h1g)
    lin_out<<<dim3(T_SEQ), dim3(64), 0, stream>>>(h1g, w_lin, b_lin, out);
}